// Round 10
// baseline (2044.423 us; speedup 1.0000x reference)
//
#include <hip/hip_runtime.h>

#define CAPS_EPS 1e-8f

typedef __attribute__((ext_vector_type(8))) short short8;
typedef __attribute__((ext_vector_type(4))) float f32x4;

__device__ inline ushort bf16_rn(float f) {
    uint u = __float_as_uint(f);
    u += 0x7fff + ((u >> 16) & 1);
    return (ushort)(u >> 16);
}
__device__ inline float bf16_f(ushort h) { return __uint_as_float((uint)h << 16); }

// async global->LDS DMA, 16B per lane. LDS dst = wave-uniform base + lane*16.
__device__ __forceinline__ void gld16(const void* g, void* l) {
    __builtin_amdgcn_global_load_lds(
        (const __attribute__((address_space(1))) unsigned int*)g,
        (__attribute__((address_space(3))) unsigned int*)l, 16, 0, 0);
}

// ============================================================
// Layouts:
//   wBhi/wBlo [256 n][20736 k] bf16, k = (ky*9+kx)*256 + c
//   h1hi/h1lo [512][20][20][256] bf16 (NHWC)
//   h2  [512*36][256] fp32
//   xhi/xlo, w1phi/plo alias h2 region (dead once k_h2init4 runs)
//   uT [9216][512]; bl [11520][512]; Z [10][512]; sT/v/vT [160][512]
//   sT holds UN-normalized stilde = sum_i exp(bl)*uhat; k_v/k_predv divide by Z.
//   bf16 hi/lo: dec/r1/r2 activations + decoder weights live in h1 region post-conv2.
// ============================================================

// ---------- fused pre-pass: w2 transpose+split | x split | w1 pad+split ----------
__global__ __launch_bounds__(256) void k_pre(const float* __restrict__ w2,
                                             ushort* __restrict__ wBhi,
                                             ushort* __restrict__ wBlo,
                                             const float* __restrict__ x,
                                             ushort* __restrict__ xhi,
                                             ushort* __restrict__ xlo,
                                             const float* __restrict__ w1,
                                             ushort* __restrict__ w1phi,
                                             ushort* __restrict__ w1plo) {
    int bx = blockIdx.x, tid = threadIdx.x;
    if (bx < 256) {
        __shared__ float ld[81 * 65];
        int n = bx;
        const float* src = w2 + (size_t)n * 20736;
        for (int cc = 0; cc < 4; ++cc) {
            for (int i = tid; i < 5184; i += 256) {
                int c_loc = i / 81, t = i - c_loc * 81;
                ld[t * 65 + c_loc] = src[cc * 5184 + i];
            }
            __syncthreads();
            for (int i = tid; i < 5184; i += 256) {
                int t = i >> 6, c_loc = i & 63;
                float f = ld[t * 65 + c_loc];
                ushort hi = bf16_rn(f);
                ushort lo = bf16_rn(f - bf16_f(hi));
                size_t o = (size_t)n * 20736 + t * 256 + cc * 64 + c_loc;
                wBhi[o] = hi;
                wBlo[o] = lo;
            }
            __syncthreads();
        }
    } else if (bx < 256 + 1569) {
        int idx = (bx - 256) * 256 + tid;
        if (idx < 401408) {
            float f = x[idx];
            ushort hi = bf16_rn(f);
            ushort lo = bf16_rn(f - bf16_f(hi));
            xhi[idx] = hi;
            xlo[idx] = lo;
        } else if (idx < 401472) {
            xhi[idx] = 0;
            xlo[idx] = 0;
        }
    } else {
        int idx = (bx - 1825) * 256 + tid;      // [0, 40960)
        int c = idx / 160;
        int kk160 = idx - c * 160;
        int kstep = kk160 >> 5, kk = kk160 & 31;
        int ky = kstep * 2 + (kk >> 4), kx = kk & 15;
        float f = (ky < 9 && kx < 9) ? w1[c * 81 + ky * 9 + kx] : 0.f;
        ushort hi = bf16_rn(f);
        ushort lo = bf16_rn(f - bf16_f(hi));
        w1phi[idx] = hi;
        w1plo[idx] = lo;
    }
}

// ---------- conv1 as split-bf16 MFMA implicit GEMM ----------
__global__ __launch_bounds__(256) void k_conv1m(const ushort* __restrict__ xhi,
                                                const ushort* __restrict__ xlo,
                                                const ushort* __restrict__ w1phi,
                                                const ushort* __restrict__ w1plo,
                                                const float* __restrict__ b1,
                                                ushort* __restrict__ h1hi,
                                                ushort* __restrict__ h1lo) {
    int tid = threadIdx.x;
    int wv = tid >> 6, lane = tid & 63;
    int lrow = lane & 15, quad = lane >> 4;
    int m0 = blockIdx.x * 128 + wv * 32;
    int c0 = blockIdx.y * 64;

    int am[2];
#pragma unroll
    for (int t = 0; t < 2; ++t) {
        int m = m0 + t * 16 + lrow;
        int b = m / 400, r = m - b * 400;
        int y = r / 20, xx = r - y * 20;
        am[t] = b * 784 + y * 28 + xx;
    }

    f32x4 acc[2][4];
#pragma unroll
    for (int t = 0; t < 2; ++t)
#pragma unroll
        for (int tn = 0; tn < 4; ++tn) acc[t][tn] = (f32x4){0.f, 0.f, 0.f, 0.f};

    for (int kstep = 0; kstep < 5; ++kstep) {
        int arow = (kstep * 2 + (quad >> 1)) * 28 + (quad & 1) * 8;
        int boff = kstep * 32 + quad * 8;
        short8 bh[4], bl2[4];
#pragma unroll
        for (int tn = 0; tn < 4; ++tn) {
            int br = (c0 + tn * 16 + lrow) * 160 + boff;
            bh[tn] = *reinterpret_cast<const short8*>(w1phi + br);
            bl2[tn] = *reinterpret_cast<const short8*>(w1plo + br);
        }
#pragma unroll
        for (int t = 0; t < 2; ++t) {
            short8 ah = *reinterpret_cast<const short8*>(xhi + am[t] + arow);
            short8 al = *reinterpret_cast<const short8*>(xlo + am[t] + arow);
#pragma unroll
            for (int tn = 0; tn < 4; ++tn) {
                acc[t][tn] = __builtin_amdgcn_mfma_f32_16x16x32_bf16(ah, bh[tn], acc[t][tn], 0, 0, 0);
                acc[t][tn] = __builtin_amdgcn_mfma_f32_16x16x32_bf16(ah, bl2[tn], acc[t][tn], 0, 0, 0);
                acc[t][tn] = __builtin_amdgcn_mfma_f32_16x16x32_bf16(al, bh[tn], acc[t][tn], 0, 0, 0);
            }
        }
    }

#pragma unroll
    for (int t = 0; t < 2; ++t)
#pragma unroll
        for (int r = 0; r < 4; ++r) {
            int m = m0 + t * 16 + quad * 4 + r;
#pragma unroll
            for (int tn = 0; tn < 4; ++tn) {
                int c = c0 + tn * 16 + lrow;
                float v = acc[t][tn][r] + b1[c];
                v = fmaxf(v, 0.f);
                ushort hi = bf16_rn(v);
                ushort lo = bf16_rn(v - bf16_f(hi));
                h1hi[(size_t)m * 256 + c] = hi;
                h1lo[(size_t)m * 256 + c] = lo;
            }
        }
}

// ---------- h2 init with bias, float4-wide (AFTER conv1m) ----------
__global__ __launch_bounds__(256) void k_h2init4(const float* __restrict__ b2,
                                                 float* __restrict__ h2) {
    size_t idx = (size_t)blockIdx.x * 256 + threadIdx.x;   // [0, 1179648)
    const float4* b24 = reinterpret_cast<const float4*>(b2);
    reinterpret_cast<float4*>(h2)[idx] = b24[idx & 63];
}

// ---------- conv2: split-bf16 MFMA implicit GEMM ----------
// 128m x 256n tile, BK=32, K-split 8.  LDS 40 KB (Ahi DMA + Bhi/Blo DMA);
// a_lo fragments loaded DIRECTLY from global (short8, L2-hot, reused 8x from regs)
// -> up to 4 blocks/CU co-resident to hide the barrier vmcnt drain.
__global__ __launch_bounds__(256, 3) void k_conv2m(const ushort* __restrict__ h1hi,
                                                   const ushort* __restrict__ h1lo,
                                                   const ushort* __restrict__ wBhi,
                                                   const ushort* __restrict__ wBlo,
                                                   float* __restrict__ h2) {
    __shared__ ushort Ahi[128 * 32];   // 8 KB
    __shared__ ushort Bhi[256 * 32];   // 16 KB
    __shared__ ushort Blo[256 * 32];   // 16 KB
    int tid = threadIdx.x;
    int m0 = blockIdx.x * 128;
    int kbase = blockIdx.y * 2592;          // 20736 / 8

    int wv = tid >> 6, lane = tid & 63;
    int cq = (lane & 3) * 8;

    // A-hi DMA: wave wv stages rows [32wv, 32wv+32); 2 instrs of 16 rows each.
    int ra = wv * 32 + (lane >> 2);
    int mA0 = m0 + ra, mA1 = mA0 + 16;
    int mb0 = mA0 / 36, mp0 = mA0 - mb0 * 36;
    int mb1 = mA1 / 36, mp1 = mA1 - mb1 * 36;
    size_t a0 = ((size_t)mb0 * 400 + (mp0 / 6) * 40 + (mp0 % 6) * 2) * 256 + cq;
    size_t a1 = ((size_t)mb1 * 400 + (mp1 / 6) * 40 + (mp1 % 6) * 2) * 256 + cq;
    int ldsA = wv * 1024;

    // B DMA: wave wv stages rows [64wv, 64wv+64); 4 instrs of 16 rows each.
    int rb = wv * 64 + (lane >> 2);
    size_t bB = (size_t)rb * 20736 + cq;
    int ldsB = wv * 2048;

    // frag mapping: wave covers 64m x 128n quadrant
    int mhalf = (wv >> 1) * 64, nhalf = (wv & 1) * 128;
    int lrow = lane & 15, quad = lane >> 4;

    // per-lane im2col bases for the 4 a_lo fragment rows (direct global loads)
    size_t aL[4];
#pragma unroll
    for (int tm = 0; tm < 4; ++tm) {
        int m = m0 + mhalf + tm * 16 + lrow;
        int b = m / 36, p = m - b * 36;
        int oy = p / 6, ox = p - oy * 6;
        aL[tm] = ((size_t)b * 400 + oy * 40 + ox * 2) * 256 + quad * 8;
    }

    f32x4 acc[4][8];
#pragma unroll
    for (int a = 0; a < 4; ++a)
#pragma unroll
        for (int bq = 0; bq < 8; ++bq) acc[a][bq] = (f32x4){0.f, 0.f, 0.f, 0.f};

    for (int ks = 0; ks < 81; ++ks) {
        int k = kbase + ks * 32;
        int t = k >> 8, cc = k & 255;
        int ky = t / 9, kx = t - ky * 9;
        size_t koffA = (size_t)(ky * 5120 + kx * 256 + cc);

        __syncthreads();
        gld16(h1hi + a0 + koffA, &Ahi[ldsA]);
        gld16(h1hi + a1 + koffA, &Ahi[ldsA + 512]);
#pragma unroll
        for (int q = 0; q < 4; ++q) {
            size_t bo = bB + (size_t)q * 331776 + k;
            gld16(wBhi + bo, &Bhi[ldsB + q * 512]);
            gld16(wBlo + bo, &Blo[ldsB + q * 512]);
        }
        __syncthreads();

        short8 ah[4], al[4];
#pragma unroll
        for (int tm = 0; tm < 4; ++tm) {
            int off = (mhalf + tm * 16 + lrow) * 32 + quad * 8;
            ah[tm] = *reinterpret_cast<short8*>(&Ahi[off]);
            al[tm] = *reinterpret_cast<const short8*>(h1lo + aL[tm] + koffA);
        }
#pragma unroll
        for (int tn = 0; tn < 8; ++tn) {
            int off = (nhalf + tn * 16 + lrow) * 32 + quad * 8;
            short8 bh = *reinterpret_cast<short8*>(&Bhi[off]);
            short8 bl2 = *reinterpret_cast<short8*>(&Blo[off]);
#pragma unroll
            for (int tm = 0; tm < 4; ++tm) {
                acc[tm][tn] = __builtin_amdgcn_mfma_f32_16x16x32_bf16(ah[tm], bh, acc[tm][tn], 0, 0, 0);
                acc[tm][tn] = __builtin_amdgcn_mfma_f32_16x16x32_bf16(ah[tm], bl2, acc[tm][tn], 0, 0, 0);
                acc[tm][tn] = __builtin_amdgcn_mfma_f32_16x16x32_bf16(al[tm], bh, acc[tm][tn], 0, 0, 0);
            }
        }
    }

#pragma unroll
    for (int tm = 0; tm < 4; ++tm) {
        int mrow = m0 + mhalf + tm * 16 + quad * 4;
#pragma unroll
        for (int tn = 0; tn < 8; ++tn) {
            int ncol = nhalf + tn * 16 + lrow;
#pragma unroll
            for (int r = 0; r < 4; ++r)
                atomicAdd(&h2[(size_t)(mrow + r) * 256 + ncol], acc[tm][tn][r]);
        }
    }
}

// ---------- fused post-conv2 pass: squash+transpose | zero bl/sT/Z | decoder
//            weight transposes ----------
__device__ __forceinline__ void wtrans(const float* __restrict__ src,
                                       ushort* __restrict__ dh,
                                       ushort* __restrict__ dl,
                                       float* ld, int kt, int nt, int K, int N,
                                       int tid) {
    for (int i = tid; i < 4096; i += 256) {
        int kk = i >> 6, nn = i & 63;
        int k = kt * 64 + kk, n = nt * 64 + nn;
        float f = (k < K && n < N) ? src[(size_t)k * N + n] : 0.f;
        ld[kk * 65 + nn] = f;
    }
    __syncthreads();
    for (int i = tid; i < 4096; i += 256) {
        int nn = i >> 6, kk = i & 63;
        int k = kt * 64 + kk, n = nt * 64 + nn;
        if (k < K) {
            float f = ld[kk * 65 + nn];
            ushort hi = bf16_rn(f);
            ushort lo = bf16_rn(f - bf16_f(hi));
            dh[(size_t)n * K + k] = hi;
            dl[(size_t)n * K + k] = lo;
        }
    }
}

__global__ __launch_bounds__(256) void k_post(const float* __restrict__ h2,
                                              float* __restrict__ uT,
                                              float* __restrict__ zr,
                                              const float* __restrict__ d1w,
                                              const float* __restrict__ d2w,
                                              const float* __restrict__ d3w,
                                              ushort* __restrict__ d1wThi, ushort* __restrict__ d1wTlo,
                                              ushort* __restrict__ d2wThi, ushort* __restrict__ d2wTlo,
                                              ushort* __restrict__ d3wThi, ushort* __restrict__ d3wTlo) {
    __shared__ float smem[8224 + 1056];
    int bx = blockIdx.x, t = threadIdx.x;
    if (bx < 576) {
        float (*ld)[257] = (float (*)[257])smem;
        float (*scl)[33] = (float (*)[33])(smem + 8224);
        int s = bx % 36;
        int b0 = (bx / 36) * 32;
        for (int bb = 0; bb < 32; ++bb)
            ld[bb][t] = h2[((size_t)(b0 + bb) * 36 + s) * 256 + t];
        __syncthreads();
        int b = t & 31, gb = (t >> 5) * 4;
#pragma unroll
        for (int q = 0; q < 4; ++q) {
            int g = gb + q;
            float s2 = 0.f;
#pragma unroll
            for (int n = 0; n < 8; ++n) {
                float vv = ld[b][g + n * 32];
                s2 = fmaf(vv, vv, s2);
            }
            scl[b][g] = s2 / ((1.f + s2) * sqrtf(s2 + CAPS_EPS));
        }
        __syncthreads();
        int hf = t >> 5;
        for (int gg = 0; gg < 32; ++gg) {
            int idx = hf * 32 + gg;
            int g = idx >> 3, n = idx & 7;
            uT[(((size_t)g * 36 + s) * 8 + n) * 512 + b0 + b] = ld[b][g + n * 32] * scl[b][g];
        }
    } else if (bx < 6421) {
        reinterpret_cast<float4*>(zr)[(size_t)(bx - 576) * 256 + t] = make_float4(0, 0, 0, 0);
    } else if (bx < 6445) {
        int local = bx - 6421;                 // 3 x 8
        wtrans(d1w, d1wThi, d1wTlo, smem, local / 8, local % 8, 160, 512, t);
    } else if (bx < 6573) {
        int local = bx - 6445;                 // 8 x 16
        wtrans(d2w, d2wThi, d2wTlo, smem, local / 16, local % 16, 512, 1024, t);
    } else {
        int local = bx - 6573;                 // 16 x 14
        wtrans(d3w, d3wThi, d3wTlo, smem, local / 14, local % 14, 1024, 784, t);
    }
}

// ---------- stilde[b,j,m] = sum_i ctilde * (W u), ctilde = exp(bl) (or 1 it0) ----------
__global__ __launch_bounds__(256) void k_s(const float* __restrict__ Wc,
                                           const float* __restrict__ uT,
                                           const float* __restrict__ bl,
                                           float* __restrict__ sT,
                                           int first) {
    __shared__ float lw[8 * 1280];
    int tid = threadIdx.x;
    int i0 = blockIdx.x * 8;
    int b = blockIdx.y * 128 + (tid & 127);
    int mh = tid >> 7;
    const float* wg = Wc + (size_t)i0 * 1280;
#pragma unroll
    for (int r = 0; r < 10; ++r) {
        int q4 = (r * 256 + tid) * 4;
        *reinterpret_cast<float4*>(&lw[q4]) = *reinterpret_cast<const float4*>(wg + q4);
    }
    __syncthreads();
    float acc[80];
#pragma unroll
    for (int q = 0; q < 80; ++q) acc[q] = 0.f;
    for (int di = 0; di < 8; ++di) {
        int i = i0 + di;
        float ur[8];
#pragma unroll
        for (int n = 0; n < 8; ++n) ur[n] = uT[((size_t)i * 8 + n) * 512 + b];
#pragma unroll
        for (int j = 0; j < 10; ++j) {
            float c;
            if (first) c = 1.0f;
            else c = expf(bl[((size_t)i * 10 + j) * 512 + b]);
            const float* wp = &lw[(di * 10 + j) * 128 + mh * 8];
            float4 s0 = {0.f, 0.f, 0.f, 0.f}, s1 = {0.f, 0.f, 0.f, 0.f};
#pragma unroll
            for (int n = 0; n < 8; ++n) {
                const float4* wq = reinterpret_cast<const float4*>(wp + n * 16);
                float4 wa = wq[0], wb = wq[1];
                float un = ur[n];
                s0.x = fmaf(un, wa.x, s0.x); s0.y = fmaf(un, wa.y, s0.y);
                s0.z = fmaf(un, wa.z, s0.z); s0.w = fmaf(un, wa.w, s0.w);
                s1.x = fmaf(un, wb.x, s1.x); s1.y = fmaf(un, wb.y, s1.y);
                s1.z = fmaf(un, wb.z, s1.z); s1.w = fmaf(un, wb.w, s1.w);
            }
            acc[j * 8 + 0] = fmaf(c, s0.x, acc[j * 8 + 0]);
            acc[j * 8 + 1] = fmaf(c, s0.y, acc[j * 8 + 1]);
            acc[j * 8 + 2] = fmaf(c, s0.z, acc[j * 8 + 2]);
            acc[j * 8 + 3] = fmaf(c, s0.w, acc[j * 8 + 3]);
            acc[j * 8 + 4] = fmaf(c, s1.x, acc[j * 8 + 4]);
            acc[j * 8 + 5] = fmaf(c, s1.y, acc[j * 8 + 5]);
            acc[j * 8 + 6] = fmaf(c, s1.z, acc[j * 8 + 6]);
            acc[j * 8 + 7] = fmaf(c, s1.w, acc[j * 8 + 7]);
        }
    }
#pragma unroll
    for (int j = 0; j < 10; ++j)
#pragma unroll
        for (int mm = 0; mm < 8; ++mm)
            atomicAdd(&sT[(j * 16 + mh * 8 + mm) * 512 + b], acc[j * 8 + mm]);
}

// ---------- v = squash(stilde/Z); write v, vT; zero sT and Z ----------
__global__ __launch_bounds__(256) void k_v(const float* __restrict__ sT,
                                           const float* __restrict__ Z,
                                           float* __restrict__ v,
                                           float* __restrict__ vT,
                                           float* __restrict__ sTz,
                                           float* __restrict__ Zz,
                                           int first) {
    int idx = blockIdx.x * 256 + threadIdx.x;   // 5120
    int j = idx >> 9;
    int b = idx & 511;
    float rz = first ? (1.0f / 1152.0f) : (1.0f / Z[j * 512 + b]);
    float sv[16];
    float s2 = 0.f;
#pragma unroll
    for (int m = 0; m < 16; ++m) {
        sv[m] = sT[(j * 16 + m) * 512 + b] * rz;
        s2 = fmaf(sv[m], sv[m], s2);
    }
    float scale = s2 / ((1.f + s2) * sqrtf(s2 + CAPS_EPS));
#pragma unroll
    for (int m = 0; m < 16; ++m) {
        float val = sv[m] * scale;
        v[(size_t)b * 160 + j * 16 + m] = val;
        vT[(j * 16 + m) * 512 + b] = val;
        sTz[(j * 16 + m) * 512 + b] = 0.f;
    }
    Zz[idx] = 0.f;
}

// ---------- b_log += u . (W v); accumulate Z = sum_i exp(b_log_new) ----------
__global__ __launch_bounds__(256) void k_bupd(const float* __restrict__ Wc,
                                              const float* __restrict__ uT,
                                              const float* __restrict__ vT,
                                              float* __restrict__ bl,
                                              float* __restrict__ Z) {
    __shared__ float lw[8 * 1280];
    int tid = threadIdx.x;
    int i0 = blockIdx.x * 8;
    int b = blockIdx.y * 128 + (tid & 127);
    int ih = tid >> 7;
    const float* wg = Wc + (size_t)i0 * 1280;
#pragma unroll
    for (int r = 0; r < 10; ++r) {
        int q4 = (r * 256 + tid) * 4;
        *reinterpret_cast<float4*>(&lw[q4]) = *reinterpret_cast<const float4*>(wg + q4);
    }
    __syncthreads();
    float ur[4][8];
#pragma unroll
    for (int ii = 0; ii < 4; ++ii) {
        int i = i0 + ih * 4 + ii;
#pragma unroll
        for (int n = 0; n < 8; ++n) ur[ii][n] = uT[((size_t)i * 8 + n) * 512 + b];
    }
    for (int j = 0; j < 10; ++j) {
        float vj[16];
#pragma unroll
        for (int m = 0; m < 16; ++m) vj[m] = vT[(j * 16 + m) * 512 + b];
        float zp = 0.f;
#pragma unroll
        for (int ii = 0; ii < 4; ++ii) {
            int di = ih * 4 + ii;
            const float* wp = &lw[(di * 10 + j) * 128];
            float t = 0.f;
#pragma unroll
            for (int n = 0; n < 8; ++n) {
                const float4* wq = reinterpret_cast<const float4*>(wp + n * 16);
                float4 w0 = wq[0], w1 = wq[1], w2 = wq[2], w3 = wq[3];
                float wvv = w0.x * vj[0];
                wvv = fmaf(w0.y, vj[1], wvv);  wvv = fmaf(w0.z, vj[2], wvv);
                wvv = fmaf(w0.w, vj[3], wvv);  wvv = fmaf(w1.x, vj[4], wvv);
                wvv = fmaf(w1.y, vj[5], wvv);  wvv = fmaf(w1.z, vj[6], wvv);
                wvv = fmaf(w1.w, vj[7], wvv);  wvv = fmaf(w2.x, vj[8], wvv);
                wvv = fmaf(w2.y, vj[9], wvv);  wvv = fmaf(w2.z, vj[10], wvv);
                wvv = fmaf(w2.w, vj[11], wvv); wvv = fmaf(w3.x, vj[12], wvv);
                wvv = fmaf(w3.y, vj[13], wvv); wvv = fmaf(w3.z, vj[14], wvv);
                wvv = fmaf(w3.w, vj[15], wvv);
                t = fmaf(ur[ii][n], wvv, t);
            }
            size_t idx = ((size_t)(i0 + di) * 10 + j) * 512 + b;
            float nb = bl[idx] + t;
            bl[idx] = nb;
            zp += expf(nb);
        }
        atomicAdd(&Z[j * 512 + b], zp);
    }
}

// ---------- final iter: v = squash(stilde/Z), caps->out, pred, masked dec ----------
__global__ __launch_bounds__(256) void k_predv(const float* __restrict__ sT,
                                               const float* __restrict__ Z,
                                               float* __restrict__ out,
                                               ushort* __restrict__ dechi,
                                               ushort* __restrict__ declo,
                                               int pred_off) {
    int b = blockIdx.x, t = threadIdx.x;
    __shared__ float sq[160];
    __shared__ float nrm[10];
    __shared__ float scl[10];
    __shared__ float vnrm[10];
    __shared__ int ip;
    float raw = 0.f;
    int j = t >> 4;
    if (t < 160) {
        raw = sT[(size_t)t * 512 + b] / Z[j * 512 + b];
        sq[t] = raw * raw;
    }
    __syncthreads();
    if (t < 10) {
        float s = 0.f;
#pragma unroll
        for (int k = 0; k < 16; ++k) s += sq[t * 16 + k];
        nrm[t] = s;
        float sc = s / ((1.f + s) * sqrtf(s + CAPS_EPS));
        scl[t] = sc;
        vnrm[t] = s * sc * sc;        // |v_j|^2
    }
    __syncthreads();
    float val = 0.f;
    if (t < 160) {
        val = raw * scl[j];
        out[(size_t)b * 160 + t] = val;
    }
    if (t == 0) {
        float best = vnrm[0];
        int bi = 0;
        for (int jj = 1; jj < 10; ++jj)
            if (vnrm[jj] > best) { best = vnrm[jj]; bi = jj; }
        ip = bi;
        out[(size_t)pred_off + b] = (float)bi;
    }
    __syncthreads();
    if (t < 160) {
        float d = (j == ip) ? val : 0.f;
        ushort hi = bf16_rn(d);
        ushort lo = bf16_rn(d - bf16_f(hi));
        dechi[(size_t)b * 160 + t] = hi;
        declo[(size_t)b * 160 + t] = lo;
    }
}

// ---------- decoder GEMM, split-bf16 MFMA, direct global frag loads ----------
template <int ACT, int SPLIT_OUT>
__global__ __launch_bounds__(256) void k_gemmm(const ushort* __restrict__ Ahi,
                                               const ushort* __restrict__ Alo,
                                               const ushort* __restrict__ Bhi,
                                               const ushort* __restrict__ Blo,
                                               const float* __restrict__ bias,
                                               ushort* __restrict__ Chi,
                                               ushort* __restrict__ Clo,
                                               float* __restrict__ Cf,
                                               int K, int Ng) {
    int tid = threadIdx.x;
    int wv = tid >> 6, lane = tid & 63;
    int lrow = lane & 15, quad = lane >> 4;
    int m0 = blockIdx.x * 64 + (wv >> 1) * 32;
    int n0 = blockIdx.y * 128 + (wv & 1) * 64;

    f32x4 acc[2][4];
#pragma unroll
    for (int t = 0; t < 2; ++t)
#pragma unroll
        for (int tn = 0; tn < 4; ++tn) acc[t][tn] = (f32x4){0.f, 0.f, 0.f, 0.f};

    for (int ks = 0; ks < K; ks += 32) {
        int boff = ks + quad * 8;
        short8 bh[4], bl2[4];
#pragma unroll
        for (int tn = 0; tn < 4; ++tn) {
            size_t br = (size_t)(n0 + tn * 16 + lrow) * K + boff;
            bh[tn] = *reinterpret_cast<const short8*>(Bhi + br);
            bl2[tn] = *reinterpret_cast<const short8*>(Blo + br);
        }
#pragma unroll
        for (int t = 0; t < 2; ++t) {
            size_t ar = (size_t)(m0 + t * 16 + lrow) * K + boff;
            short8 ah = *reinterpret_cast<const short8*>(Ahi + ar);
            short8 al = *reinterpret_cast<const short8*>(Alo + ar);
#pragma unroll
            for (int tn = 0; tn < 4; ++tn) {
                acc[t][tn] = __builtin_amdgcn_mfma_f32_16x16x32_bf16(ah, bh[tn], acc[t][tn], 0, 0, 0);
                acc[t][tn] = __builtin_amdgcn_mfma_f32_16x16x32_bf16(ah, bl2[tn], acc[t][tn], 0, 0, 0);
                acc[t][tn] = __builtin_amdgcn_mfma_f32_16x16x32_bf16(al, bh[tn], acc[t][tn], 0, 0, 0);
            }
        }
    }

#pragma unroll
    for (int t = 0; t < 2; ++t)
#pragma unroll
        for (int r = 0; r < 4; ++r) {
            int m = m0 + t * 16 + quad * 4 + r;
#pragma unroll
            for (int tn = 0; tn < 4; ++tn) {
                int n = n0 + tn * 16 + lrow;
                if (n < Ng) {
                    float val = acc[t][tn][r] + bias[n];
                    if (ACT == 0) val = fmaxf(val, 0.f);
                    else val = 1.f / (1.f + expf(-val));
                    if (SPLIT_OUT) {
                        ushort hi = bf16_rn(val);
                        ushort lo = bf16_rn(val - bf16_f(hi));
                        Chi[(size_t)m * Ng + n] = hi;
                        Clo[(size_t)m * Ng + n] = lo;
                    } else {
                        Cf[(size_t)m * Ng + n] = val;
                    }
                }
            }
        }
}

extern "C" void kernel_launch(void* const* d_in, const int* in_sizes, int n_in,
                              void* d_out, int out_size, void* d_ws, size_t ws_size,
                              hipStream_t stream) {
    const float* x   = (const float*)d_in[0];
    const float* w1  = (const float*)d_in[1];
    const float* b1  = (const float*)d_in[2];
    const float* w2  = (const float*)d_in[3];
    const float* b2  = (const float*)d_in[4];
    const float* Wc  = (const float*)d_in[5];
    const float* d1w = (const float*)d_in[6];
    const float* d1b = (const float*)d_in[7];
    const float* d2w = (const float*)d_in[8];
    const float* d2b = (const float*)d_in[9];
    const float* d3w = (const float*)d_in[10];
    const float* d3b = (const float*)d_in[11];
    float* out = (float*)d_out;

    // ---- workspace: wB [0,21.2M) | h1 [21.2M,230.9M) | h2 [230.9M,249.8M)
    ushort* wBhi = (ushort*)d_ws;
    ushort* wBlo = wBhi + 5308416;
    ushort* h1hi = (ushort*)((char*)d_ws + 21233664);
    ushort* h1lo = h1hi + 52428800;
    char*   h2b  = (char*)d_ws + 230948864;
    float*  h2   = (float*)h2b;
    // phase-1 aliases inside the h2 region (dead once k_h2init4 runs):
    ushort* xhi   = (ushort*)h2b;
    ushort* xlo   = xhi + 401472;
    ushort* w1phi = xlo + 401472;
    ushort* w1plo = w1phi + 40960;

    // post-conv2 aliases inside h1 region (write only after k_conv2m)
    float* post = (float*)((char*)d_ws + 21233664);
    float* uT  = post + 4718592;
    float* bl  = post + 9437184;         // bl+sT+Z contiguous 5,985,280 f
    float* sT  = post + 15335424;
    float* Z   = post + 15417344;
    float* v   = post + 15422464;
    float* vT  = post + 15504384;
    ushort* ub = (ushort*)(post + 15586304);
    ushort* dechi   = ub;                  // 512x160
    ushort* declo   = ub + 81920;
    ushort* r1hi    = ub + 163840;         // 512x512
    ushort* r1lo    = ub + 425984;
    ushort* r2hi    = ub + 688128;         // 512x1024
    ushort* r2lo    = ub + 1212416;
    ushort* d1wThi  = ub + 1736704;        // 512x160
    ushort* d1wTlo  = ub + 1818624;
    ushort* d2wThi  = ub + 1900544;        // 1024x512
    ushort* d2wTlo  = ub + 2424832;
    ushort* d3wThi  = ub + 2949120;        // 896x1024 (n padded)
    ushort* d3wTlo  = ub + 3866624;

    int pred_off = out_size - 512;

    k_pre<<<1985, 256, 0, stream>>>(w2, wBhi, wBlo, x, xhi, xlo, w1, w1phi, w1plo);
    k_conv1m<<<dim3(1600, 4), 256, 0, stream>>>(xhi, xlo, w1phi, w1plo, b1, h1hi, h1lo);
    k_h2init4<<<4608, 256, 0, stream>>>(b2, h2);
    k_conv2m<<<dim3(144, 8), 256, 0, stream>>>(h1hi, h1lo, wBhi, wBlo, h2);
    k_post<<<6797, 256, 0, stream>>>(h2, uT, bl, d1w, d2w, d3w,
                                     d1wThi, d1wTlo, d2wThi, d2wTlo, d3wThi, d3wTlo);

    // routing: it0, it1 with k_v; it2 folds squash+pred into k_predv
    k_s<<<dim3(144, 4), 256, 0, stream>>>(Wc, uT, bl, sT, 1);
    k_v<<<20, 256, 0, stream>>>(sT, Z, v, vT, sT, Z, 1);
    k_bupd<<<dim3(144, 4), 256, 0, stream>>>(Wc, uT, vT, bl, Z);
    k_s<<<dim3(144, 4), 256, 0, stream>>>(Wc, uT, bl, sT, 0);
    k_v<<<20, 256, 0, stream>>>(sT, Z, v, vT, sT, Z, 0);
    k_bupd<<<dim3(144, 4), 256, 0, stream>>>(Wc, uT, vT, bl, Z);
    k_s<<<dim3(144, 4), 256, 0, stream>>>(Wc, uT, bl, sT, 0);
    k_predv<<<512, 256, 0, stream>>>(sT, Z, out, dechi, declo, pred_off);

    k_gemmm<0, 1><<<dim3(8, 4), 256, 0, stream>>>(dechi, declo, d1wThi, d1wTlo, d1b,
                                                  r1hi, r1lo, nullptr, 160, 512);
    k_gemmm<0, 1><<<dim3(8, 8), 256, 0, stream>>>(r1hi, r1lo, d2wThi, d2wTlo, d2b,
                                                  r2hi, r2lo, nullptr, 512, 1024);
    k_gemmm<1, 0><<<dim3(8, 7), 256, 0, stream>>>(r2hi, r2lo, d3wThi, d3wTlo, d3b,
                                                  nullptr, nullptr, out + 81920, 1024, 784);
}

// Round 11
// 1344.051 us; speedup vs baseline: 1.5211x; 1.5211x over previous
//
#include <hip/hip_runtime.h>

#define CAPS_EPS 1e-8f

typedef __attribute__((ext_vector_type(8))) short short8;
typedef __attribute__((ext_vector_type(4))) float f32x4;

__device__ inline ushort bf16_rn(float f) {
    uint u = __float_as_uint(f);
    u += 0x7fff + ((u >> 16) & 1);
    return (ushort)(u >> 16);
}
__device__ inline float bf16_f(ushort h) { return __uint_as_float((uint)h << 16); }

// async global->LDS DMA, 16B per lane. LDS dst = wave-uniform base + lane*16.
__device__ __forceinline__ void gld16(const void* g, void* l) {
    __builtin_amdgcn_global_load_lds(
        (const __attribute__((address_space(1))) unsigned int*)g,
        (__attribute__((address_space(3))) unsigned int*)l, 16, 0, 0);
}

// ============================================================
// Layouts:
//   wBhi/wBlo [256 n][20736 k] bf16, k = (ky*9+kx)*256 + c
//   h1hi/h1lo [512][20][20][256] bf16 (NHWC)
//   h2  [512*36][256] fp32
//   xhi/xlo, w1phi/plo alias h2 region (dead once k_h2init4 runs)
//   uT [9216][512]; bl [11520][512]; Z [10][512]; sT/v/vT [160][512]
//   sT holds UN-normalized stilde = sum_i exp(bl)*uhat; k_v/k_predv divide by Z.
//   bf16 hi/lo: dec/r1/r2 activations + decoder weights live in h1 region post-conv2.
// NOTE (R10 lesson): a_lo MUST be DMA-staged; direct per-lane global frag loads
//   tripled HBM FETCH (792MB->2.47GB) and 9x'd WRITE via L2 thrash.
// ============================================================

// ---------- fused pre-pass: w2 transpose+split | x split | w1 pad+split ----------
__global__ __launch_bounds__(256) void k_pre(const float* __restrict__ w2,
                                             ushort* __restrict__ wBhi,
                                             ushort* __restrict__ wBlo,
                                             const float* __restrict__ x,
                                             ushort* __restrict__ xhi,
                                             ushort* __restrict__ xlo,
                                             const float* __restrict__ w1,
                                             ushort* __restrict__ w1phi,
                                             ushort* __restrict__ w1plo) {
    int bx = blockIdx.x, tid = threadIdx.x;
    if (bx < 256) {
        __shared__ float ld[81 * 65];
        int n = bx;
        const float* src = w2 + (size_t)n * 20736;
        for (int cc = 0; cc < 4; ++cc) {
            for (int i = tid; i < 5184; i += 256) {
                int c_loc = i / 81, t = i - c_loc * 81;
                ld[t * 65 + c_loc] = src[cc * 5184 + i];
            }
            __syncthreads();
            for (int i = tid; i < 5184; i += 256) {
                int t = i >> 6, c_loc = i & 63;
                float f = ld[t * 65 + c_loc];
                ushort hi = bf16_rn(f);
                ushort lo = bf16_rn(f - bf16_f(hi));
                size_t o = (size_t)n * 20736 + t * 256 + cc * 64 + c_loc;
                wBhi[o] = hi;
                wBlo[o] = lo;
            }
            __syncthreads();
        }
    } else if (bx < 256 + 1569) {
        int idx = (bx - 256) * 256 + tid;
        if (idx < 401408) {
            float f = x[idx];
            ushort hi = bf16_rn(f);
            ushort lo = bf16_rn(f - bf16_f(hi));
            xhi[idx] = hi;
            xlo[idx] = lo;
        } else if (idx < 401472) {
            xhi[idx] = 0;
            xlo[idx] = 0;
        }
    } else {
        int idx = (bx - 1825) * 256 + tid;      // [0, 40960)
        int c = idx / 160;
        int kk160 = idx - c * 160;
        int kstep = kk160 >> 5, kk = kk160 & 31;
        int ky = kstep * 2 + (kk >> 4), kx = kk & 15;
        float f = (ky < 9 && kx < 9) ? w1[c * 81 + ky * 9 + kx] : 0.f;
        ushort hi = bf16_rn(f);
        ushort lo = bf16_rn(f - bf16_f(hi));
        w1phi[idx] = hi;
        w1plo[idx] = lo;
    }
}

// ---------- conv1 as split-bf16 MFMA implicit GEMM ----------
__global__ __launch_bounds__(256) void k_conv1m(const ushort* __restrict__ xhi,
                                                const ushort* __restrict__ xlo,
                                                const ushort* __restrict__ w1phi,
                                                const ushort* __restrict__ w1plo,
                                                const float* __restrict__ b1,
                                                ushort* __restrict__ h1hi,
                                                ushort* __restrict__ h1lo) {
    int tid = threadIdx.x;
    int wv = tid >> 6, lane = tid & 63;
    int lrow = lane & 15, quad = lane >> 4;
    int m0 = blockIdx.x * 128 + wv * 32;
    int c0 = blockIdx.y * 64;

    int am[2];
#pragma unroll
    for (int t = 0; t < 2; ++t) {
        int m = m0 + t * 16 + lrow;
        int b = m / 400, r = m - b * 400;
        int y = r / 20, xx = r - y * 20;
        am[t] = b * 784 + y * 28 + xx;
    }

    f32x4 acc[2][4];
#pragma unroll
    for (int t = 0; t < 2; ++t)
#pragma unroll
        for (int tn = 0; tn < 4; ++tn) acc[t][tn] = (f32x4){0.f, 0.f, 0.f, 0.f};

    for (int kstep = 0; kstep < 5; ++kstep) {
        int arow = (kstep * 2 + (quad >> 1)) * 28 + (quad & 1) * 8;
        int boff = kstep * 32 + quad * 8;
        short8 bh[4], bl2[4];
#pragma unroll
        for (int tn = 0; tn < 4; ++tn) {
            int br = (c0 + tn * 16 + lrow) * 160 + boff;
            bh[tn] = *reinterpret_cast<const short8*>(w1phi + br);
            bl2[tn] = *reinterpret_cast<const short8*>(w1plo + br);
        }
#pragma unroll
        for (int t = 0; t < 2; ++t) {
            short8 ah = *reinterpret_cast<const short8*>(xhi + am[t] + arow);
            short8 al = *reinterpret_cast<const short8*>(xlo + am[t] + arow);
#pragma unroll
            for (int tn = 0; tn < 4; ++tn) {
                acc[t][tn] = __builtin_amdgcn_mfma_f32_16x16x32_bf16(ah, bh[tn], acc[t][tn], 0, 0, 0);
                acc[t][tn] = __builtin_amdgcn_mfma_f32_16x16x32_bf16(ah, bl2[tn], acc[t][tn], 0, 0, 0);
                acc[t][tn] = __builtin_amdgcn_mfma_f32_16x16x32_bf16(al, bh[tn], acc[t][tn], 0, 0, 0);
            }
        }
    }

#pragma unroll
    for (int t = 0; t < 2; ++t)
#pragma unroll
        for (int r = 0; r < 4; ++r) {
            int m = m0 + t * 16 + quad * 4 + r;
#pragma unroll
            for (int tn = 0; tn < 4; ++tn) {
                int c = c0 + tn * 16 + lrow;
                float v = acc[t][tn][r] + b1[c];
                v = fmaxf(v, 0.f);
                ushort hi = bf16_rn(v);
                ushort lo = bf16_rn(v - bf16_f(hi));
                h1hi[(size_t)m * 256 + c] = hi;
                h1lo[(size_t)m * 256 + c] = lo;
            }
        }
}

// ---------- h2 init with bias, float4-wide (AFTER conv1m) ----------
__global__ __launch_bounds__(256) void k_h2init4(const float* __restrict__ b2,
                                                 float* __restrict__ h2) {
    size_t idx = (size_t)blockIdx.x * 256 + threadIdx.x;   // [0, 1179648)
    const float4* b24 = reinterpret_cast<const float4*>(b2);
    reinterpret_cast<float4*>(h2)[idx] = b24[idx & 63];
}

// ---------- conv2: split-bf16 MFMA implicit GEMM, global_load_lds staging ----------
// C[18432][256] += A(im2col h1) * B.  Tile 128m x 256n (FULL N), BK=32, K-split 8.
// Proven config (R8 bench: 587 us, MfmaUtil 45%, FETCH 765 MB): all four arrays
// DMA-staged, 48 KB LDS, 2 blocks/CU, m-fastest grid.
__global__ __launch_bounds__(256, 2) void k_conv2m(const ushort* __restrict__ h1hi,
                                                   const ushort* __restrict__ h1lo,
                                                   const ushort* __restrict__ wBhi,
                                                   const ushort* __restrict__ wBlo,
                                                   float* __restrict__ h2) {
    __shared__ ushort Ahi[128 * 32];   // 8 KB
    __shared__ ushort Alo[128 * 32];   // 8 KB
    __shared__ ushort Bhi[256 * 32];   // 16 KB
    __shared__ ushort Blo[256 * 32];   // 16 KB
    int tid = threadIdx.x;
    int m0 = blockIdx.x * 128;
    int kbase = blockIdx.y * 2592;          // 20736 / 8

    int wv = tid >> 6, lane = tid & 63;
    int cq = (lane & 3) * 8;

    // A DMA: wave wv stages rows [32wv, 32wv+32); 2 instrs of 16 rows each.
    int ra = wv * 32 + (lane >> 2);
    int mA0 = m0 + ra, mA1 = mA0 + 16;
    int mb0 = mA0 / 36, mp0 = mA0 - mb0 * 36;
    int mb1 = mA1 / 36, mp1 = mA1 - mb1 * 36;
    size_t a0 = ((size_t)mb0 * 400 + (mp0 / 6) * 40 + (mp0 % 6) * 2) * 256 + cq;
    size_t a1 = ((size_t)mb1 * 400 + (mp1 / 6) * 40 + (mp1 % 6) * 2) * 256 + cq;
    int ldsA = wv * 1024;

    // B DMA: wave wv stages rows [64wv, 64wv+64); 4 instrs of 16 rows each.
    int rb = wv * 64 + (lane >> 2);
    size_t bB = (size_t)rb * 20736 + cq;
    int ldsB = wv * 2048;

    // frag mapping: wave covers 64m x 128n quadrant
    int mhalf = (wv >> 1) * 64, nhalf = (wv & 1) * 128;
    int lrow = lane & 15, quad = lane >> 4;

    f32x4 acc[4][8];
#pragma unroll
    for (int a = 0; a < 4; ++a)
#pragma unroll
        for (int bq = 0; bq < 8; ++bq) acc[a][bq] = (f32x4){0.f, 0.f, 0.f, 0.f};

    for (int ks = 0; ks < 81; ++ks) {
        int k = kbase + ks * 32;
        int t = k >> 8, cc = k & 255;
        int ky = t / 9, kx = t - ky * 9;
        size_t koffA = (size_t)(ky * 5120 + kx * 256 + cc);

        __syncthreads();
        gld16(h1hi + a0 + koffA, &Ahi[ldsA]);
        gld16(h1hi + a1 + koffA, &Ahi[ldsA + 512]);
        gld16(h1lo + a0 + koffA, &Alo[ldsA]);
        gld16(h1lo + a1 + koffA, &Alo[ldsA + 512]);
#pragma unroll
        for (int q = 0; q < 4; ++q) {
            size_t bo = bB + (size_t)q * 331776 + k;
            gld16(wBhi + bo, &Bhi[ldsB + q * 512]);
            gld16(wBlo + bo, &Blo[ldsB + q * 512]);
        }
        __syncthreads();

        short8 ah[4], al[4];
#pragma unroll
        for (int tm = 0; tm < 4; ++tm) {
            int off = (mhalf + tm * 16 + lrow) * 32 + quad * 8;
            ah[tm] = *reinterpret_cast<short8*>(&Ahi[off]);
            al[tm] = *reinterpret_cast<short8*>(&Alo[off]);
        }
#pragma unroll
        for (int tn = 0; tn < 8; ++tn) {
            int off = (nhalf + tn * 16 + lrow) * 32 + quad * 8;
            short8 bh = *reinterpret_cast<short8*>(&Bhi[off]);
            short8 bl2 = *reinterpret_cast<short8*>(&Blo[off]);
#pragma unroll
            for (int tm = 0; tm < 4; ++tm) {
                acc[tm][tn] = __builtin_amdgcn_mfma_f32_16x16x32_bf16(ah[tm], bh, acc[tm][tn], 0, 0, 0);
                acc[tm][tn] = __builtin_amdgcn_mfma_f32_16x16x32_bf16(ah[tm], bl2, acc[tm][tn], 0, 0, 0);
                acc[tm][tn] = __builtin_amdgcn_mfma_f32_16x16x32_bf16(al[tm], bh, acc[tm][tn], 0, 0, 0);
            }
        }
    }

#pragma unroll
    for (int tm = 0; tm < 4; ++tm) {
        int mrow = m0 + mhalf + tm * 16 + quad * 4;
#pragma unroll
        for (int tn = 0; tn < 8; ++tn) {
            int ncol = nhalf + tn * 16 + lrow;
#pragma unroll
            for (int r = 0; r < 4; ++r)
                atomicAdd(&h2[(size_t)(mrow + r) * 256 + ncol], acc[tm][tn][r]);
        }
    }
}

// ---------- fused post-conv2 pass: squash+transpose | zero bl/sT/Z | decoder
//            weight transposes ----------
__device__ __forceinline__ void wtrans(const float* __restrict__ src,
                                       ushort* __restrict__ dh,
                                       ushort* __restrict__ dl,
                                       float* ld, int kt, int nt, int K, int N,
                                       int tid) {
    for (int i = tid; i < 4096; i += 256) {
        int kk = i >> 6, nn = i & 63;
        int k = kt * 64 + kk, n = nt * 64 + nn;
        float f = (k < K && n < N) ? src[(size_t)k * N + n] : 0.f;
        ld[kk * 65 + nn] = f;
    }
    __syncthreads();
    for (int i = tid; i < 4096; i += 256) {
        int nn = i >> 6, kk = i & 63;
        int k = kt * 64 + kk, n = nt * 64 + nn;
        if (k < K) {
            float f = ld[kk * 65 + nn];
            ushort hi = bf16_rn(f);
            ushort lo = bf16_rn(f - bf16_f(hi));
            dh[(size_t)n * K + k] = hi;
            dl[(size_t)n * K + k] = lo;
        }
    }
}

__global__ __launch_bounds__(256) void k_post(const float* __restrict__ h2,
                                              float* __restrict__ uT,
                                              float* __restrict__ zr,
                                              const float* __restrict__ d1w,
                                              const float* __restrict__ d2w,
                                              const float* __restrict__ d3w,
                                              ushort* __restrict__ d1wThi, ushort* __restrict__ d1wTlo,
                                              ushort* __restrict__ d2wThi, ushort* __restrict__ d2wTlo,
                                              ushort* __restrict__ d3wThi, ushort* __restrict__ d3wTlo) {
    __shared__ float smem[8224 + 1056];
    int bx = blockIdx.x, t = threadIdx.x;
    if (bx < 576) {
        float (*ld)[257] = (float (*)[257])smem;
        float (*scl)[33] = (float (*)[33])(smem + 8224);
        int s = bx % 36;
        int b0 = (bx / 36) * 32;
        for (int bb = 0; bb < 32; ++bb)
            ld[bb][t] = h2[((size_t)(b0 + bb) * 36 + s) * 256 + t];
        __syncthreads();
        int b = t & 31, gb = (t >> 5) * 4;
#pragma unroll
        for (int q = 0; q < 4; ++q) {
            int g = gb + q;
            float s2 = 0.f;
#pragma unroll
            for (int n = 0; n < 8; ++n) {
                float vv = ld[b][g + n * 32];
                s2 = fmaf(vv, vv, s2);
            }
            scl[b][g] = s2 / ((1.f + s2) * sqrtf(s2 + CAPS_EPS));
        }
        __syncthreads();
        int hf = t >> 5;
        for (int gg = 0; gg < 32; ++gg) {
            int idx = hf * 32 + gg;
            int g = idx >> 3, n = idx & 7;
            uT[(((size_t)g * 36 + s) * 8 + n) * 512 + b0 + b] = ld[b][g + n * 32] * scl[b][g];
        }
    } else if (bx < 6421) {
        reinterpret_cast<float4*>(zr)[(size_t)(bx - 576) * 256 + t] = make_float4(0, 0, 0, 0);
    } else if (bx < 6445) {
        int local = bx - 6421;                 // 3 x 8
        wtrans(d1w, d1wThi, d1wTlo, smem, local / 8, local % 8, 160, 512, t);
    } else if (bx < 6573) {
        int local = bx - 6445;                 // 8 x 16
        wtrans(d2w, d2wThi, d2wTlo, smem, local / 16, local % 16, 512, 1024, t);
    } else {
        int local = bx - 6573;                 // 16 x 14
        wtrans(d3w, d3wThi, d3wTlo, smem, local / 14, local % 14, 1024, 784, t);
    }
}

// ---------- stilde[b,j,m] = sum_i ctilde * (W u), ctilde = exp(bl) (or 1 it0) ----------
__global__ __launch_bounds__(256) void k_s(const float* __restrict__ Wc,
                                           const float* __restrict__ uT,
                                           const float* __restrict__ bl,
                                           float* __restrict__ sT,
                                           int first) {
    __shared__ float lw[8 * 1280];
    int tid = threadIdx.x;
    int i0 = blockIdx.x * 8;
    int b = blockIdx.y * 128 + (tid & 127);
    int mh = tid >> 7;
    const float* wg = Wc + (size_t)i0 * 1280;
#pragma unroll
    for (int r = 0; r < 10; ++r) {
        int q4 = (r * 256 + tid) * 4;
        *reinterpret_cast<float4*>(&lw[q4]) = *reinterpret_cast<const float4*>(wg + q4);
    }
    __syncthreads();
    float acc[80];
#pragma unroll
    for (int q = 0; q < 80; ++q) acc[q] = 0.f;
    for (int di = 0; di < 8; ++di) {
        int i = i0 + di;
        float ur[8];
#pragma unroll
        for (int n = 0; n < 8; ++n) ur[n] = uT[((size_t)i * 8 + n) * 512 + b];
#pragma unroll
        for (int j = 0; j < 10; ++j) {
            float c;
            if (first) c = 1.0f;
            else c = expf(bl[((size_t)i * 10 + j) * 512 + b]);
            const float* wp = &lw[(di * 10 + j) * 128 + mh * 8];
            float4 s0 = {0.f, 0.f, 0.f, 0.f}, s1 = {0.f, 0.f, 0.f, 0.f};
#pragma unroll
            for (int n = 0; n < 8; ++n) {
                const float4* wq = reinterpret_cast<const float4*>(wp + n * 16);
                float4 wa = wq[0], wb = wq[1];
                float un = ur[n];
                s0.x = fmaf(un, wa.x, s0.x); s0.y = fmaf(un, wa.y, s0.y);
                s0.z = fmaf(un, wa.z, s0.z); s0.w = fmaf(un, wa.w, s0.w);
                s1.x = fmaf(un, wb.x, s1.x); s1.y = fmaf(un, wb.y, s1.y);
                s1.z = fmaf(un, wb.z, s1.z); s1.w = fmaf(un, wb.w, s1.w);
            }
            acc[j * 8 + 0] = fmaf(c, s0.x, acc[j * 8 + 0]);
            acc[j * 8 + 1] = fmaf(c, s0.y, acc[j * 8 + 1]);
            acc[j * 8 + 2] = fmaf(c, s0.z, acc[j * 8 + 2]);
            acc[j * 8 + 3] = fmaf(c, s0.w, acc[j * 8 + 3]);
            acc[j * 8 + 4] = fmaf(c, s1.x, acc[j * 8 + 4]);
            acc[j * 8 + 5] = fmaf(c, s1.y, acc[j * 8 + 5]);
            acc[j * 8 + 6] = fmaf(c, s1.z, acc[j * 8 + 6]);
            acc[j * 8 + 7] = fmaf(c, s1.w, acc[j * 8 + 7]);
        }
    }
#pragma unroll
    for (int j = 0; j < 10; ++j)
#pragma unroll
        for (int mm = 0; mm < 8; ++mm)
            atomicAdd(&sT[(j * 16 + mh * 8 + mm) * 512 + b], acc[j * 8 + mm]);
}

// ---------- v = squash(stilde/Z); write v, vT; zero sT and Z ----------
__global__ __launch_bounds__(256) void k_v(const float* __restrict__ sT,
                                           const float* __restrict__ Z,
                                           float* __restrict__ v,
                                           float* __restrict__ vT,
                                           float* __restrict__ sTz,
                                           float* __restrict__ Zz,
                                           int first) {
    int idx = blockIdx.x * 256 + threadIdx.x;   // 5120
    int j = idx >> 9;
    int b = idx & 511;
    float rz = first ? (1.0f / 1152.0f) : (1.0f / Z[j * 512 + b]);
    float sv[16];
    float s2 = 0.f;
#pragma unroll
    for (int m = 0; m < 16; ++m) {
        sv[m] = sT[(j * 16 + m) * 512 + b] * rz;
        s2 = fmaf(sv[m], sv[m], s2);
    }
    float scale = s2 / ((1.f + s2) * sqrtf(s2 + CAPS_EPS));
#pragma unroll
    for (int m = 0; m < 16; ++m) {
        float val = sv[m] * scale;
        v[(size_t)b * 160 + j * 16 + m] = val;
        vT[(j * 16 + m) * 512 + b] = val;
        sTz[(j * 16 + m) * 512 + b] = 0.f;
    }
    Zz[idx] = 0.f;
}

// ---------- b_log += u . (W v); accumulate Z = sum_i exp(b_log_new) ----------
__global__ __launch_bounds__(256) void k_bupd(const float* __restrict__ Wc,
                                              const float* __restrict__ uT,
                                              const float* __restrict__ vT,
                                              float* __restrict__ bl,
                                              float* __restrict__ Z) {
    __shared__ float lw[8 * 1280];
    int tid = threadIdx.x;
    int i0 = blockIdx.x * 8;
    int b = blockIdx.y * 128 + (tid & 127);
    int ih = tid >> 7;
    const float* wg = Wc + (size_t)i0 * 1280;
#pragma unroll
    for (int r = 0; r < 10; ++r) {
        int q4 = (r * 256 + tid) * 4;
        *reinterpret_cast<float4*>(&lw[q4]) = *reinterpret_cast<const float4*>(wg + q4);
    }
    __syncthreads();
    float ur[4][8];
#pragma unroll
    for (int ii = 0; ii < 4; ++ii) {
        int i = i0 + ih * 4 + ii;
#pragma unroll
        for (int n = 0; n < 8; ++n) ur[ii][n] = uT[((size_t)i * 8 + n) * 512 + b];
    }
    for (int j = 0; j < 10; ++j) {
        float vj[16];
#pragma unroll
        for (int m = 0; m < 16; ++m) vj[m] = vT[(j * 16 + m) * 512 + b];
        float zp = 0.f;
#pragma unroll
        for (int ii = 0; ii < 4; ++ii) {
            int di = ih * 4 + ii;
            const float* wp = &lw[(di * 10 + j) * 128];
            float t = 0.f;
#pragma unroll
            for (int n = 0; n < 8; ++n) {
                const float4* wq = reinterpret_cast<const float4*>(wp + n * 16);
                float4 w0 = wq[0], w1 = wq[1], w2 = wq[2], w3 = wq[3];
                float wvv = w0.x * vj[0];
                wvv = fmaf(w0.y, vj[1], wvv);  wvv = fmaf(w0.z, vj[2], wvv);
                wvv = fmaf(w0.w, vj[3], wvv);  wvv = fmaf(w1.x, vj[4], wvv);
                wvv = fmaf(w1.y, vj[5], wvv);  wvv = fmaf(w1.z, vj[6], wvv);
                wvv = fmaf(w1.w, vj[7], wvv);  wvv = fmaf(w2.x, vj[8], wvv);
                wvv = fmaf(w2.y, vj[9], wvv);  wvv = fmaf(w2.z, vj[10], wvv);
                wvv = fmaf(w2.w, vj[11], wvv); wvv = fmaf(w3.x, vj[12], wvv);
                wvv = fmaf(w3.y, vj[13], wvv); wvv = fmaf(w3.z, vj[14], wvv);
                wvv = fmaf(w3.w, vj[15], wvv);
                t = fmaf(ur[ii][n], wvv, t);
            }
            size_t idx = ((size_t)(i0 + di) * 10 + j) * 512 + b;
            float nb = bl[idx] + t;
            bl[idx] = nb;
            zp += expf(nb);
        }
        atomicAdd(&Z[j * 512 + b], zp);
    }
}

// ---------- final iter: v = squash(stilde/Z), caps->out, pred, masked dec ----------
__global__ __launch_bounds__(256) void k_predv(const float* __restrict__ sT,
                                               const float* __restrict__ Z,
                                               float* __restrict__ out,
                                               ushort* __restrict__ dechi,
                                               ushort* __restrict__ declo,
                                               int pred_off) {
    int b = blockIdx.x, t = threadIdx.x;
    __shared__ float sq[160];
    __shared__ float scl[10];
    __shared__ float vnrm[10];
    __shared__ int ip;
    float raw = 0.f;
    int j = t >> 4;
    if (t < 160) {
        raw = sT[(size_t)t * 512 + b] / Z[j * 512 + b];
        sq[t] = raw * raw;
    }
    __syncthreads();
    if (t < 10) {
        float s = 0.f;
#pragma unroll
        for (int k = 0; k < 16; ++k) s += sq[t * 16 + k];
        float sc = s / ((1.f + s) * sqrtf(s + CAPS_EPS));
        scl[t] = sc;
        vnrm[t] = s * sc * sc;        // |v_j|^2
    }
    __syncthreads();
    float val = 0.f;
    if (t < 160) {
        val = raw * scl[j];
        out[(size_t)b * 160 + t] = val;
    }
    if (t == 0) {
        float best = vnrm[0];
        int bi = 0;
        for (int jj = 1; jj < 10; ++jj)
            if (vnrm[jj] > best) { best = vnrm[jj]; bi = jj; }
        ip = bi;
        out[(size_t)pred_off + b] = (float)bi;
    }
    __syncthreads();
    if (t < 160) {
        float d = (j == ip) ? val : 0.f;
        ushort hi = bf16_rn(d);
        ushort lo = bf16_rn(d - bf16_f(hi));
        dechi[(size_t)b * 160 + t] = hi;
        declo[(size_t)b * 160 + t] = lo;
    }
}

// ---------- decoder GEMM, split-bf16 MFMA, direct global frag loads ----------
template <int ACT, int SPLIT_OUT>
__global__ __launch_bounds__(256) void k_gemmm(const ushort* __restrict__ Ahi,
                                               const ushort* __restrict__ Alo,
                                               const ushort* __restrict__ Bhi,
                                               const ushort* __restrict__ Blo,
                                               const float* __restrict__ bias,
                                               ushort* __restrict__ Chi,
                                               ushort* __restrict__ Clo,
                                               float* __restrict__ Cf,
                                               int K, int Ng) {
    int tid = threadIdx.x;
    int wv = tid >> 6, lane = tid & 63;
    int lrow = lane & 15, quad = lane >> 4;
    int m0 = blockIdx.x * 64 + (wv >> 1) * 32;
    int n0 = blockIdx.y * 128 + (wv & 1) * 64;

    f32x4 acc[2][4];
#pragma unroll
    for (int t = 0; t < 2; ++t)
#pragma unroll
        for (int tn = 0; tn < 4; ++tn) acc[t][tn] = (f32x4){0.f, 0.f, 0.f, 0.f};

    for (int ks = 0; ks < K; ks += 32) {
        int boff = ks + quad * 8;
        short8 bh[4], bl2[4];
#pragma unroll
        for (int tn = 0; tn < 4; ++tn) {
            size_t br = (size_t)(n0 + tn * 16 + lrow) * K + boff;
            bh[tn] = *reinterpret_cast<const short8*>(Bhi + br);
            bl2[tn] = *reinterpret_cast<const short8*>(Blo + br);
        }
#pragma unroll
        for (int t = 0; t < 2; ++t) {
            size_t ar = (size_t)(m0 + t * 16 + lrow) * K + boff;
            short8 ah = *reinterpret_cast<const short8*>(Ahi + ar);
            short8 al = *reinterpret_cast<const short8*>(Alo + ar);
#pragma unroll
            for (int tn = 0; tn < 4; ++tn) {
                acc[t][tn] = __builtin_amdgcn_mfma_f32_16x16x32_bf16(ah, bh[tn], acc[t][tn], 0, 0, 0);
                acc[t][tn] = __builtin_amdgcn_mfma_f32_16x16x32_bf16(ah, bl2[tn], acc[t][tn], 0, 0, 0);
                acc[t][tn] = __builtin_amdgcn_mfma_f32_16x16x32_bf16(al, bh[tn], acc[t][tn], 0, 0, 0);
            }
        }
    }

#pragma unroll
    for (int t = 0; t < 2; ++t)
#pragma unroll
        for (int r = 0; r < 4; ++r) {
            int m = m0 + t * 16 + quad * 4 + r;
#pragma unroll
            for (int tn = 0; tn < 4; ++tn) {
                int n = n0 + tn * 16 + lrow;
                if (n < Ng) {
                    float val = acc[t][tn][r] + bias[n];
                    if (ACT == 0) val = fmaxf(val, 0.f);
                    else val = 1.f / (1.f + expf(-val));
                    if (SPLIT_OUT) {
                        ushort hi = bf16_rn(val);
                        ushort lo = bf16_rn(val - bf16_f(hi));
                        Chi[(size_t)m * Ng + n] = hi;
                        Clo[(size_t)m * Ng + n] = lo;
                    } else {
                        Cf[(size_t)m * Ng + n] = val;
                    }
                }
            }
        }
}

extern "C" void kernel_launch(void* const* d_in, const int* in_sizes, int n_in,
                              void* d_out, int out_size, void* d_ws, size_t ws_size,
                              hipStream_t stream) {
    const float* x   = (const float*)d_in[0];
    const float* w1  = (const float*)d_in[1];
    const float* b1  = (const float*)d_in[2];
    const float* w2  = (const float*)d_in[3];
    const float* b2  = (const float*)d_in[4];
    const float* Wc  = (const float*)d_in[5];
    const float* d1w = (const float*)d_in[6];
    const float* d1b = (const float*)d_in[7];
    const float* d2w = (const float*)d_in[8];
    const float* d2b = (const float*)d_in[9];
    const float* d3w = (const float*)d_in[10];
    const float* d3b = (const float*)d_in[11];
    float* out = (float*)d_out;

    // ---- workspace: wB [0,21.2M) | h1 [21.2M,230.9M) | h2 [230.9M,249.8M)
    ushort* wBhi = (ushort*)d_ws;
    ushort* wBlo = wBhi + 5308416;
    ushort* h1hi = (ushort*)((char*)d_ws + 21233664);
    ushort* h1lo = h1hi + 52428800;
    char*   h2b  = (char*)d_ws + 230948864;
    float*  h2   = (float*)h2b;
    // phase-1 aliases inside the h2 region (dead once k_h2init4 runs):
    ushort* xhi   = (ushort*)h2b;
    ushort* xlo   = xhi + 401472;
    ushort* w1phi = xlo + 401472;
    ushort* w1plo = w1phi + 40960;

    // post-conv2 aliases inside h1 region (write only after k_conv2m)
    float* post = (float*)((char*)d_ws + 21233664);
    float* uT  = post + 4718592;
    float* bl  = post + 9437184;         // bl+sT+Z contiguous 5,985,280 f
    float* sT  = post + 15335424;
    float* Z   = post + 15417344;
    float* v   = post + 15422464;
    float* vT  = post + 15504384;
    ushort* ub = (ushort*)(post + 15586304);
    ushort* dechi   = ub;                  // 512x160
    ushort* declo   = ub + 81920;
    ushort* r1hi    = ub + 163840;         // 512x512
    ushort* r1lo    = ub + 425984;
    ushort* r2hi    = ub + 688128;         // 512x1024
    ushort* r2lo    = ub + 1212416;
    ushort* d1wThi  = ub + 1736704;        // 512x160
    ushort* d1wTlo  = ub + 1818624;
    ushort* d2wThi  = ub + 1900544;        // 1024x512
    ushort* d2wTlo  = ub + 2424832;
    ushort* d3wThi  = ub + 2949120;        // 896x1024 (n padded)
    ushort* d3wTlo  = ub + 3866624;

    int pred_off = out_size - 512;

    k_pre<<<1985, 256, 0, stream>>>(w2, wBhi, wBlo, x, xhi, xlo, w1, w1phi, w1plo);
    k_conv1m<<<dim3(1600, 4), 256, 0, stream>>>(xhi, xlo, w1phi, w1plo, b1, h1hi, h1lo);
    k_h2init4<<<4608, 256, 0, stream>>>(b2, h2);
    k_conv2m<<<dim3(144, 8), 256, 0, stream>>>(h1hi, h1lo, wBhi, wBlo, h2);
    k_post<<<6797, 256, 0, stream>>>(h2, uT, bl, d1w, d2w, d3w,
                                     d1wThi, d1wTlo, d2wThi, d2wTlo, d3wThi, d3wTlo);

    // routing: it0, it1 with k_v; it2 folds squash+pred into k_predv
    k_s<<<dim3(144, 4), 256, 0, stream>>>(Wc, uT, bl, sT, 1);
    k_v<<<20, 256, 0, stream>>>(sT, Z, v, vT, sT, Z, 1);
    k_bupd<<<dim3(144, 4), 256, 0, stream>>>(Wc, uT, vT, bl, Z);
    k_s<<<dim3(144, 4), 256, 0, stream>>>(Wc, uT, bl, sT, 0);
    k_v<<<20, 256, 0, stream>>>(sT, Z, v, vT, sT, Z, 0);
    k_bupd<<<dim3(144, 4), 256, 0, stream>>>(Wc, uT, vT, bl, Z);
    k_s<<<dim3(144, 4), 256, 0, stream>>>(Wc, uT, bl, sT, 0);
    k_predv<<<512, 256, 0, stream>>>(sT, Z, out, dechi, declo, pred_off);

    k_gemmm<0, 1><<<dim3(8, 4), 256, 0, stream>>>(dechi, declo, d1wThi, d1wTlo, d1b,
                                                  r1hi, r1lo, nullptr, 160, 512);
    k_gemmm<0, 1><<<dim3(8, 8), 256, 0, stream>>>(r1hi, r1lo, d2wThi, d2wTlo, d2b,
                                                  r2hi, r2lo, nullptr, 512, 1024);
    k_gemmm<1, 0><<<dim3(8, 7), 256, 0, stream>>>(r2hi, r2lo, d3wThi, d3wTlo, d3b,
                                                  nullptr, nullptr, out + 81920, 1024, 784);
}